// Round 1
// baseline (1471.567 us; speedup 1.0000x reference)
//
#include <hip/hip_runtime.h>
#include <math.h>

// Problem constants (fixed by setup_inputs)
#define BB   32
#define HQ   32
#define HKV  8
#define DD   128
#define PAGE 16
#define GRP  4   // HQ / HKV

// Async global->LDS DMA, 16 B per lane. LDS dest is wave-uniform base + lane*16.
__device__ __forceinline__ void async_ld16(const float* g, float* l) {
    __builtin_amdgcn_global_load_lds(
        (__attribute__((address_space(1))) void*)(g),
        (__attribute__((address_space(3))) void*)(l),
        16, 0, 0);
}

// One block per (b, kv_head). 256 threads = 4 waves; wave w handles query head h*4+w.
__global__ __launch_bounds__(256) void paged_decode(
    const float* __restrict__ q,        // [B, HQ, 1, D]
    const float* __restrict__ kv,       // [NPAGES, 2, HKV, PAGE, D]
    const int*  __restrict__ indptr,    // [B+1]
    const int*  __restrict__ indices,   // [NPAGES]
    const int*  __restrict__ lastlen,   // [B]
    float* __restrict__ out)            // [B, HQ, 1, D]
{
    __shared__ __align__(16) float sK[2][PAGE * DD];   // 2 x 8 KiB
    __shared__ __align__(16) float sV[2][PAGE * DD];   // 2 x 8 KiB

    const int tid  = threadIdx.x;
    const int w    = tid >> 6;     // wave id 0..3
    const int lane = tid & 63;
    const int r    = lane >> 2;    // row 0..15
    const int sub  = lane & 3;     // 4 lanes per row

    const int b  = blockIdx.x >> 3;
    const int h  = blockIdx.x & 7;
    const int qh = h * GRP + w;

    // q fragment, column-rotated by 4*r so LDS K reads are bank-conflict-free:
    // lane covers columns {(sub*32 + 4r + 4i) mod 128 .. +3}, i = 0..7
    const float* qb = q + (size_t)(b * HQ + qh) * DD;
    float4 qv[8];
#pragma unroll
    for (int i = 0; i < 8; ++i) {
        int c = (sub * 32 + 4 * r + 4 * i) & 127;
        qv[i] = *(const float4*)(qb + c);
    }

    const int start = indptr[b];
    const int np    = indptr[b + 1] - start;   // 256 here
    const int ll    = lastlen[b];

    // Prefetch page 0 into buffer 0. Each wave DMAs 2 KiB of K and 2 KiB of V.
    {
        const int pid0 = indices[start];
        const float* base = kv + (size_t)pid0 * (2 * HKV * PAGE * DD) + h * (PAGE * DD);
        const int c0 = w * 2;  // chunk index (256 floats per chunk)
        async_ld16(base + c0 * 256 + lane * 4,                 &sK[0][c0 * 256]);
        async_ld16(base + c0 * 256 + 256 + lane * 4,           &sK[0][c0 * 256 + 256]);
        async_ld16(base + HKV * PAGE * DD + c0 * 256 + lane * 4,       &sV[0][c0 * 256]);
        async_ld16(base + HKV * PAGE * DD + c0 * 256 + 256 + lane * 4, &sV[0][c0 * 256 + 256]);
    }
    int pid_next = (np > 1) ? indices[start + 1] : 0;

    float m = -INFINITY;
    float l = 0.0f;
    float ox = 0.0f, oy = 0.0f;
    const float scale = 0.08838834764831845f;  // 1/sqrt(128)

    for (int j = 0; j < np; ++j) {
        __syncthreads();   // drains DMA for buffer j&1 (and fences LDS)
        const int buf = j & 1;

        // Prefetch page j+1 into the other buffer; in flight during compute below.
        if (j + 1 < np) {
            const float* base = kv + (size_t)pid_next * (2 * HKV * PAGE * DD) + h * (PAGE * DD);
            const int c0 = w * 2;
            float* kb = &sK[buf ^ 1][0];
            float* vb = &sV[buf ^ 1][0];
            async_ld16(base + c0 * 256 + lane * 4,                 kb + c0 * 256);
            async_ld16(base + c0 * 256 + 256 + lane * 4,           kb + c0 * 256 + 256);
            async_ld16(base + HKV * PAGE * DD + c0 * 256 + lane * 4,       vb + c0 * 256);
            async_ld16(base + HKV * PAGE * DD + c0 * 256 + 256 + lane * 4, vb + c0 * 256 + 256);
        }
        pid_next = (j + 2 < np) ? indices[start + j + 2] : 0;

        const float* Kb = sK[buf];
        const float* Vb = sV[buf];

        // Scores: lane does a 32-elem partial dot of K[r] with q (rotated cols).
        float acc = 0.0f;
#pragma unroll
        for (int i = 0; i < 8; ++i) {
            int c = (sub * 32 + 4 * r + 4 * i) & 127;
            float4 k4 = *(const float4*)(Kb + r * DD + c);
            acc += k4.x * qv[i].x + k4.y * qv[i].y + k4.z * qv[i].z + k4.w * qv[i].w;
        }
        acc += __shfl_xor(acc, 1, 64);
        acc += __shfl_xor(acc, 2, 64);
        float s = acc * scale;
        if ((j == np - 1) && (r >= ll)) s = -INFINITY;   // truncated last page

        // Page max over the 16 rows (values replicated across sub lanes).
        float pm = s;
        pm = fmaxf(pm, __shfl_xor(pm, 4, 64));
        pm = fmaxf(pm, __shfl_xor(pm, 8, 64));
        pm = fmaxf(pm, __shfl_xor(pm, 16, 64));
        pm = fmaxf(pm, __shfl_xor(pm, 32, 64));
        const float m_new = fmaxf(m, pm);
        const float p     = __expf(s - m_new);  // 0 for masked rows
        const float alpha = __expf(m - m_new);  // 0 on first page (m = -inf)
        m = m_new;

        float ps = p;
        ps += __shfl_xor(ps, 4, 64);
        ps += __shfl_xor(ps, 8, 64);
        ps += __shfl_xor(ps, 16, 64);
        ps += __shfl_xor(ps, 32, 64);
        l = l * alpha + ps;

        // O accumulation: lane owns columns {2*lane, 2*lane+1}.
        ox *= alpha; oy *= alpha;
        const float* vrow = Vb + lane * 2;
#pragma unroll
        for (int rr = 0; rr < 16; ++rr) {
            float pr = __shfl(p, rr * 4, 64);        // broadcast p[rr]
            float2 v2 = *(const float2*)(vrow + rr * DD);
            ox += pr * v2.x;
            oy += pr * v2.y;
        }
    }

    const float inv = 1.0f / l;
    float2 res; res.x = ox * inv; res.y = oy * inv;
    *(float2*)(out + (size_t)(b * HQ + qh) * DD + lane * 2) = res;
}

extern "C" void kernel_launch(void* const* d_in, const int* in_sizes, int n_in,
                              void* d_out, int out_size, void* d_ws, size_t ws_size,
                              hipStream_t stream) {
    const float* q       = (const float*)d_in[0];
    const float* kv      = (const float*)d_in[1];
    const int*   indptr  = (const int*)d_in[2];
    const int*   indices = (const int*)d_in[3];
    const int*   lastlen = (const int*)d_in[4];
    float* out = (float*)d_out;

    dim3 grid(BB * HKV);   // 256 blocks: one per (b, kv_head)
    dim3 block(256);       // 4 waves: one per query head in the group
    hipLaunchKernelGGL(paged_decode, grid, block, 0, stream,
                       q, kv, indptr, indices, lastlen, out);
}